// Round 1
// baseline (4002.990 us; speedup 1.0000x reference)
//
#include <hip/hip_runtime.h>

static constexpr int EN   = 524288;
static constexpr int NUE_ = 512;
static constexpr int NAP_ = 1024;
static constexpr int HID_ = 32;
static constexpr int OD_  = 60;   // OC - D
static constexpr int OC_  = 64;

// acc[KOUT] += seg[k] * W[(krow0+k)*KOUT + o]   (W access is wave-uniform -> s_load)
template<int L, int KOUT>
__device__ __forceinline__ void accum_seg(const float* __restrict__ W, int krow0,
                                          const float* seg, float* acc) {
  static_assert(L % 4 == 0, "segment length must be multiple of 4");
  #pragma unroll 1
  for (int k = 0; k < L; k += 4) {
    const float4 x = *reinterpret_cast<const float4*>(seg + k);
    const float xs[4] = {x.x, x.y, x.z, x.w};
    const float* __restrict__ wr = W + (size_t)(krow0 + k) * KOUT;
    #pragma unroll
    for (int j = 0; j < 4; ++j) {
      #pragma unroll
      for (int o = 0; o < KOUT; ++o)
        acc[o] = fmaf(xs[j], wr[j * KOUT + o], acc[o]);
    }
  }
}

// Fused per-edge kernel: message MLP -> atomic scatter into agg, plus edge-weight MLP.
// FUSE=true additionally runs the power head (Lin->LN->LReLU->Lin) and writes [E,5].
// NOTE: ea_in/ea_out may alias (in-place conv3u) -> no __restrict__ on them.
template<int LXJ, int LEA, int LXI, bool FUSE>
__global__ __launch_bounds__(256)
void edge_kernel(const float* __restrict__ x_src,
                 const float* ea_in,
                 const float* __restrict__ x_dst,
                 const int* __restrict__ src_idx,
                 const int* __restrict__ dst_idx,
                 const float* __restrict__ msg_W, const float* __restrict__ msg_b,
                 const float* __restrict__ ew_W,  const float* __restrict__ ew_b,
                 float* __restrict__ agg,
                 float* ea_out,
                 const float* __restrict__ pe1_W, const float* __restrict__ pe1_b,
                 const float* __restrict__ pe2_W, const float* __restrict__ pe2_b,
                 const float* __restrict__ ln_g,  const float* __restrict__ ln_b)
{
  const int e = blockIdx.x * blockDim.x + threadIdx.x;
  if (e >= EN) return;
  const int s = src_idx[e];
  const int d = dst_idx[e];
  const float* xj = x_src + (size_t)s * LXJ;
  const float* ea = ea_in + (size_t)e * LEA;
  const float* xi = x_dst + (size_t)d * LXI;

  // ---- message MLP: lrelu([xj, ea] @ msg_W + msg_b), scatter-add ----
  {
    float m[HID_];
    #pragma unroll
    for (int o = 0; o < HID_; ++o) m[o] = msg_b[o];
    accum_seg<LXJ, HID_>(msg_W, 0,   xj, m);
    accum_seg<LEA, HID_>(msg_W, LXJ, ea, m);
    float* aggrow = agg + (size_t)d * HID_;
    #pragma unroll
    for (int o = 0; o < HID_; ++o) {
      float v = m[o];
      v = v >= 0.f ? v : 0.1f * v;
      atomicAdd(aggrow + o, v);
    }
  }

  // ---- edge-weight MLP: lrelu([xj, ea, xi] @ ew_W + ew_b) ----
  float acc[OD_];
  #pragma unroll
  for (int o = 0; o < OD_; ++o) acc[o] = ew_b[o];
  accum_seg<LXJ, OD_>(ew_W, 0,         xj, acc);
  accum_seg<LEA, OD_>(ew_W, LXJ,       ea, acc);
  accum_seg<LXI, OD_>(ew_W, LXJ + LEA, xi, acc);
  #pragma unroll
  for (int o = 0; o < OD_; ++o) acc[o] = acc[o] >= 0.f ? acc[o] : 0.1f * acc[o];

  const float4 ea0 = *reinterpret_cast<const float4*>(ea);

  if constexpr (!FUSE) {
    float* orow = ea_out + (size_t)e * OC_;
    *reinterpret_cast<float4*>(orow) = ea0;
    #pragma unroll
    for (int o = 0; o < OD_; o += 4)
      *reinterpret_cast<float4*>(orow + 4 + o) =
          make_float4(acc[o], acc[o + 1], acc[o + 2], acc[o + 3]);
  } else {
    // power head on the new ea row [ea0, acc]: Lin(64->4) -> LN -> LReLU -> Lin(4->1)
    float v[4] = {pe1_b[0], pe1_b[1], pe1_b[2], pe1_b[3]};
    const float r0[4] = {ea0.x, ea0.y, ea0.z, ea0.w};
    #pragma unroll
    for (int k = 0; k < 4; ++k) {
      #pragma unroll
      for (int j = 0; j < 4; ++j)
        v[j] = fmaf(r0[k], pe1_W[k * 4 + j], v[j]);
    }
    #pragma unroll
    for (int k = 0; k < OD_; ++k) {
      #pragma unroll
      for (int j = 0; j < 4; ++j)
        v[j] = fmaf(acc[k], pe1_W[(4 + k) * 4 + j], v[j]);
    }
    const float mu = 0.25f * (v[0] + v[1] + v[2] + v[3]);
    float var = 0.f;
    #pragma unroll
    for (int j = 0; j < 4; ++j) { const float t = v[j] - mu; var = fmaf(t, t, var); }
    var *= 0.25f;
    const float rstd = rsqrtf(var + 1e-5f);
    float p = pe2_b[0];
    #pragma unroll
    for (int j = 0; j < 4; ++j) {
      float h = (v[j] - mu) * rstd * ln_g[j] + ln_b[j];
      h = h >= 0.f ? h : 0.1f * h;
      p = fmaf(h, pe2_W[j], p);
    }
    float* orow = ea_out + (size_t)e * 5;
    orow[0] = ea0.x; orow[1] = ea0.y; orow[2] = ea0.z; orow[3] = ea0.w; orow[4] = p;
  }
}

// Per-dst-node update: lrelu([x, agg] @ W + b) (+ residual x[:,4:]), write [x[:4], tmp]
// x_in/x_out may alias (in-place conv3) -> no __restrict__.
template<int LX, bool RES>
__global__ __launch_bounds__(256)
void node_kernel(const float* x_in,
                 const float* __restrict__ agg,
                 const float* __restrict__ W, const float* __restrict__ b,
                 float* x_out, int N)
{
  const int n = blockIdx.x * blockDim.x + threadIdx.x;
  if (n >= N) return;
  const float* x = x_in + (size_t)n * LX;
  float acc[OD_];
  #pragma unroll
  for (int o = 0; o < OD_; ++o) acc[o] = b[o];
  accum_seg<LX,   OD_>(W, 0,  x, acc);
  accum_seg<HID_, OD_>(W, LX, agg + (size_t)n * HID_, acc);
  #pragma unroll
  for (int o = 0; o < OD_; ++o) acc[o] = acc[o] >= 0.f ? acc[o] : 0.1f * acc[o];
  if constexpr (RES) {
    #pragma unroll
    for (int o = 0; o < OD_; ++o) acc[o] += x[4 + o];
  }
  const float4 x0 = *reinterpret_cast<const float4*>(x);
  float* orow = x_out + (size_t)n * OC_;
  *reinterpret_cast<float4*>(orow) = x0;
  #pragma unroll
  for (int o = 0; o < OD_; o += 4)
    *reinterpret_cast<float4*>(orow + 4 + o) =
        make_float4(acc[o], acc[o + 1], acc[o + 2], acc[o + 3]);
}

extern "C" void kernel_launch(void* const* d_in, const int* in_sizes, int n_in,
                              void* d_out, int out_size, void* d_ws, size_t ws_size,
                              hipStream_t stream)
{
  const float* x_ue    = (const float*)d_in[0];
  const float* x_ap    = (const float*)d_in[1];
  const float* ea_up   = (const float*)d_in[2];
  const float* ea_down = (const float*)d_in[3];
  const int* up_src = (const int*)d_in[4];
  const int* up_dst = (const int*)d_in[5];
  const int* dn_src = (const int*)d_in[6];
  const int* dn_dst = (const int*)d_in[7];
  const float* c1_msg_W = (const float*)d_in[8];  const float* c1_msg_b = (const float*)d_in[9];
  const float* c1_upd_W = (const float*)d_in[10]; const float* c1_upd_b = (const float*)d_in[11];
  const float* c1_ew_W  = (const float*)d_in[12]; const float* c1_ew_b  = (const float*)d_in[13];
  const float* c2_msg_W = (const float*)d_in[14]; const float* c2_msg_b = (const float*)d_in[15];
  const float* c2_upd_W = (const float*)d_in[16]; const float* c2_upd_b = (const float*)d_in[17];
  const float* c2_ew_W  = (const float*)d_in[18]; const float* c2_ew_b  = (const float*)d_in[19];
  const float* c3u_msg_W= (const float*)d_in[20]; const float* c3u_msg_b= (const float*)d_in[21];
  const float* c3u_upd_W= (const float*)d_in[22]; const float* c3u_upd_b= (const float*)d_in[23];
  const float* c3u_ew_W = (const float*)d_in[24]; const float* c3u_ew_b = (const float*)d_in[25];
  const float* c3d_msg_W= (const float*)d_in[26]; const float* c3d_msg_b= (const float*)d_in[27];
  const float* c3d_upd_W= (const float*)d_in[28]; const float* c3d_upd_b= (const float*)d_in[29];
  const float* c3d_ew_W = (const float*)d_in[30]; const float* c3d_ew_b = (const float*)d_in[31];
  const float* pe1_W = (const float*)d_in[32]; const float* pe1_b = (const float*)d_in[33];
  const float* pe2_W = (const float*)d_in[34]; const float* pe2_b = (const float*)d_in[35];
  const float* ln_g  = (const float*)d_in[36]; const float* ln_b  = (const float*)d_in[37];

  float* out    = (float*)d_out;
  float* x_ue_o = out;
  float* x_ap_o = out + (size_t)NUE_ * OC_;
  float* ea_up_o = x_ap_o + (size_t)NAP_ * OC_;
  float* ea_dn_o = ea_up_o + (size_t)EN * OC_;

  float* ws = (float*)d_ws;
  float* agg1 = ws;                          // [NAP, HID]
  float* agg2 = agg1 + (size_t)NAP_ * HID_;  // [NUE, HID]
  float* agg3 = agg2 + (size_t)NUE_ * HID_;  // [NAP, HID]
  float* agg4 = agg3 + (size_t)NAP_ * HID_;  // [NUE, HID]
  float* ea_dn_mid = agg4 + (size_t)NUE_ * HID_;  // [E, OC]

  hipMemsetAsync(ws, 0, sizeof(float) * (size_t)(NAP_ + NUE_) * 2 * HID_, stream);

  const dim3 blk(256);
  const dim3 egrid(EN / 256);

  // conv1: UE --up--> AP
  edge_kernel<4, 4, 4, false><<<egrid, blk, 0, stream>>>(
      x_ue, ea_up, x_ap, up_src, up_dst,
      c1_msg_W, c1_msg_b, c1_ew_W, c1_ew_b, agg1, ea_up_o,
      nullptr, nullptr, nullptr, nullptr, nullptr, nullptr);
  node_kernel<4, false><<<dim3(NAP_ / 256), blk, 0, stream>>>(
      x_ap, agg1, c1_upd_W, c1_upd_b, x_ap_o, NAP_);

  // conv2: AP --down--> UE
  edge_kernel<64, 4, 4, false><<<egrid, blk, 0, stream>>>(
      x_ap_o, ea_down, x_ue, dn_src, dn_dst,
      c2_msg_W, c2_msg_b, c2_ew_W, c2_ew_b, agg2, ea_dn_mid,
      nullptr, nullptr, nullptr, nullptr, nullptr, nullptr);
  node_kernel<4, false><<<dim3(NUE_ / 256), blk, 0, stream>>>(
      x_ue, agg2, c2_upd_W, c2_upd_b, x_ue_o, NUE_);

  // conv3u: UE --up--> AP (residual), ea_up updated in place
  edge_kernel<64, 64, 64, false><<<egrid, blk, 0, stream>>>(
      x_ue_o, ea_up_o, x_ap_o, up_src, up_dst,
      c3u_msg_W, c3u_msg_b, c3u_ew_W, c3u_ew_b, agg3, ea_up_o,
      nullptr, nullptr, nullptr, nullptr, nullptr, nullptr);
  node_kernel<64, true><<<dim3(NAP_ / 256), blk, 0, stream>>>(
      x_ap_o, agg3, c3u_upd_W, c3u_upd_b, x_ap_o, NAP_);

  // conv3d: AP --down--> UE (residual) + fused power head -> ea_down [E,5]
  edge_kernel<64, 64, 64, true><<<egrid, blk, 0, stream>>>(
      x_ap_o, ea_dn_mid, x_ue_o, dn_src, dn_dst,
      c3d_msg_W, c3d_msg_b, c3d_ew_W, c3d_ew_b, agg4, ea_dn_o,
      pe1_W, pe1_b, pe2_W, pe2_b, ln_g, ln_b);
  node_kernel<64, true><<<dim3(NUE_ / 256), blk, 0, stream>>>(
      x_ue_o, agg4, c3d_upd_W, c3d_upd_b, x_ue_o, NUE_);
}

// Round 3
// 1015.773 us; speedup vs baseline: 3.9408x; 3.9408x over previous
//
#include <hip/hip_runtime.h>

typedef __attribute__((ext_vector_type(8))) short bf16x8;
typedef __attribute__((ext_vector_type(4))) float f32x4;

static constexpr int EN   = 524288;
static constexpr int NUE_ = 512;
static constexpr int NAP_ = 1024;
static constexpr int HID_ = 32;
static constexpr int OD_  = 60;   // OC - D
static constexpr int OC_  = 64;

__device__ __forceinline__ unsigned short f2bf(float x) {
  unsigned int u = __float_as_uint(x);
  return (unsigned short)((u + 0x7fffu + ((u >> 16) & 1u)) >> 16);  // RNE
}

// W [KREAL][NREAL] fp32 -> out [NPAD][KP] bf16 transposed, zero-padded
template<int NPAD, int NREAL, int KP, int KREAL>
__global__ __launch_bounds__(256)
void prep_w(const float* __restrict__ W, unsigned short* __restrict__ out) {
  int i = blockIdx.x * 256 + threadIdx.x;
  if (i >= NPAD * KP) return;
  int n = i / KP, k = i - n * KP;
  float v = (n < NREAL && k < KREAL) ? W[(size_t)k * NREAL + n] : 0.f;
  out[i] = f2bf(v);
}

// Fused edge stage as gather-GEMM. Block = 256 thr = 4 waves, tile = 64 edges.
// X row = [xj | ea | xi] (bf16, LDS). ew: [64,KP]x[KP,64]; msg: [64,KMP]x[KMP,32].
// FUSE: run power head in fp32, write [E,5] only.
template<int LXJ, int LEA, int LXI, int KP, int KMP, bool FUSE>
__global__ __launch_bounds__(256)
void edge_mfma(const float* __restrict__ x_src, const float* ea_in,
               const float* __restrict__ x_dst,
               const int* __restrict__ src_idx, const int* __restrict__ dst_idx,
               const unsigned short* __restrict__ Wet, const unsigned short* __restrict__ Wmt,
               const float* __restrict__ msg_b, const float* __restrict__ ew_b,
               float* __restrict__ agg, float* ea_out,
               const float* __restrict__ pe1_W, const float* __restrict__ pe1_b,
               const float* __restrict__ pe2_W, const float* __restrict__ pe2_b,
               const float* __restrict__ ln_g,  const float* __restrict__ ln_b)
{
  constexpr int K = LXJ + LEA + LXI;
  constexpr int KPP = KP + 8;    // +16B pad -> 2-way-max LDS bank aliasing (free)
  constexpr int KMPP = KMP + 8;
  __shared__ unsigned short Xb[64 * KPP];
  __shared__ unsigned short Wels[64 * KPP];
  __shared__ unsigned short Wmls[32 * KMPP];
  __shared__ float Cst[64 * 68];
  const int t = threadIdx.x;
  const int eBase = blockIdx.x * 64;

  // weights -> LDS. uint4 = 8 ushorts; KP/8 chunks per row of the compact
  // [N][KP] source; dst row stride KPP (padded).
  for (int i = t; i < 64 * (KP / 8); i += 256) {
    int n = i / (KP / 8), c = i - n * (KP / 8);
    *reinterpret_cast<uint4*>(&Wels[n * KPP + c * 8]) =
        reinterpret_cast<const uint4*>(Wet)[i];
  }
  for (int i = t; i < 32 * (KMP / 8); i += 256) {
    int n = i / (KMP / 8), c = i - n * (KMP / 8);
    *reinterpret_cast<uint4*>(&Wmls[n * KMPP + c * 8]) =
        reinterpret_cast<const uint4*>(Wmt)[i];
  }
  // gather X rows -> bf16 LDS (all segment boundaries are multiples of 4)
  for (int i = t; i < 64 * (KP / 4); i += 256) {
    int r = i / (KP / 4), k0 = (i - r * (KP / 4)) * 4;
    int e = eBase + r;
    float4 v;
    if (k0 < LXJ)
      v = *reinterpret_cast<const float4*>(x_src + (size_t)src_idx[e] * LXJ + k0);
    else if (k0 < LXJ + LEA)
      v = *reinterpret_cast<const float4*>(ea_in + (size_t)e * LEA + (k0 - LXJ));
    else if (k0 < K)
      v = *reinterpret_cast<const float4*>(x_dst + (size_t)dst_idx[e] * LXI + (k0 - LXJ - LEA));
    else
      v = make_float4(0.f, 0.f, 0.f, 0.f);
    ushort4 o; o.x = f2bf(v.x); o.y = f2bf(v.y); o.z = f2bf(v.z); o.w = f2bf(v.w);
    *reinterpret_cast<ushort4*>(&Xb[r * KPP + k0]) = o;
  }
  __syncthreads();

  // MFMA: wave w owns edges [w*16, w*16+16)
  const int l = t & 63, w = t >> 6;
  const int lr = l & 15, lkb = l >> 4;        // A: row=lr, k-block=lkb; B: col=lr
  f32x4 accE[4] = {f32x4{0,0,0,0}, f32x4{0,0,0,0}, f32x4{0,0,0,0}, f32x4{0,0,0,0}};
  f32x4 accM[2] = {f32x4{0,0,0,0}, f32x4{0,0,0,0}};
  const unsigned short* xrow = &Xb[(w * 16 + lr) * KPP + lkb * 8];
  #pragma unroll
  for (int kk = 0; kk < KP / 32; ++kk) {
    bf16x8 a = *reinterpret_cast<const bf16x8*>(xrow + kk * 32);
    #pragma unroll
    for (int nt = 0; nt < 4; ++nt) {
      bf16x8 b = *reinterpret_cast<const bf16x8*>(&Wels[(nt * 16 + lr) * KPP + lkb * 8 + kk * 32]);
      accE[nt] = __builtin_amdgcn_mfma_f32_16x16x32_bf16(a, b, accE[nt], 0, 0, 0);
    }
    if (kk < KMP / 32) {
      #pragma unroll
      for (int nt = 0; nt < 2; ++nt) {
        bf16x8 b = *reinterpret_cast<const bf16x8*>(&Wmls[(nt * 16 + lr) * KMPP + lkb * 8 + kk * 32]);
        accM[nt] = __builtin_amdgcn_mfma_f32_16x16x32_bf16(a, b, accM[nt], 0, 0, 0);
      }
    }
  }

  // msg: bias + lrelu + scatter-add.  C/D layout: col=lane&15, row=(lane>>4)*4+reg
  #pragma unroll
  for (int r = 0; r < 4; ++r) {
    int erow = w * 16 + lkb * 4 + r;
    int dst = dst_idx[eBase + erow];
    #pragma unroll
    for (int nt = 0; nt < 2; ++nt) {
      int col = nt * 16 + lr;
      float v = accM[nt][r] + msg_b[col];
      v = v >= 0.f ? v : 0.1f * v;
      atomicAdd(&agg[(size_t)dst * HID_ + col], v);
    }
  }
  // ew: bias + lrelu -> Cst stage
  #pragma unroll
  for (int nt = 0; nt < 4; ++nt) {
    int col = nt * 16 + lr;
    float bias = col < OD_ ? ew_b[col] : 0.f;
    #pragma unroll
    for (int r = 0; r < 4; ++r) {
      int erow = w * 16 + lkb * 4 + r;
      float v = accE[nt][r] + bias;
      Cst[erow * 68 + col] = v >= 0.f ? v : 0.1f * v;
    }
  }
  __syncthreads();

  if constexpr (!FUSE) {
    // coalesced write: row = [ea[:4] fp32 passthrough | C[0:60]]
    for (int i = t; i < 64 * 16; i += 256) {
      int r = i >> 4, q = i & 15;
      size_t e = eBase + r;
      float4 v;
      if (q == 0) v = *reinterpret_cast<const float4*>(ea_in + e * LEA);
      else        v = *reinterpret_cast<const float4*>(&Cst[r * 68 + (q - 1) * 4]);
      *reinterpret_cast<float4*>(ea_out + e * OC_ + q * 4) = v;
    }
  } else {
    // power head (fp32): Lin(64->4) -> LN -> LReLU -> Lin(4->1); write [E,5]
    if (t < 64) {
      size_t e = eBase + t;
      const float* ear = ea_in + e * LEA;
      float v4[4] = {pe1_b[0], pe1_b[1], pe1_b[2], pe1_b[3]};
      #pragma unroll
      for (int k = 0; k < 4; ++k) {
        float x = ear[k];
        #pragma unroll
        for (int j = 0; j < 4; ++j) v4[j] = fmaf(x, pe1_W[k * 4 + j], v4[j]);
      }
      for (int k = 0; k < OD_; ++k) {
        float x = Cst[t * 68 + k];
        #pragma unroll
        for (int j = 0; j < 4; ++j) v4[j] = fmaf(x, pe1_W[(4 + k) * 4 + j], v4[j]);
      }
      float mu = 0.25f * (v4[0] + v4[1] + v4[2] + v4[3]);
      float var = 0.f;
      #pragma unroll
      for (int j = 0; j < 4; ++j) { float d = v4[j] - mu; var = fmaf(d, d, var); }
      var *= 0.25f;
      float rstd = rsqrtf(var + 1e-5f);
      float p = pe2_b[0];
      #pragma unroll
      for (int j = 0; j < 4; ++j) {
        float h = (v4[j] - mu) * rstd * ln_g[j] + ln_b[j];
        h = h >= 0.f ? h : 0.1f * h;
        p = fmaf(h, pe2_W[j], p);
      }
      float* orow = ea_out + e * 5;
      orow[0] = ear[0]; orow[1] = ear[1]; orow[2] = ear[2]; orow[3] = ear[3]; orow[4] = p;
    }
  }
}

// ---- scalar fp32 node update (tiny: 512/1024 rows) ----
template<int L, int KOUT>
__device__ __forceinline__ void accum_seg(const float* __restrict__ W, int krow0,
                                          const float* seg, float* acc) {
  #pragma unroll 1
  for (int k = 0; k < L; k += 4) {
    const float4 x = *reinterpret_cast<const float4*>(seg + k);
    const float xs[4] = {x.x, x.y, x.z, x.w};
    const float* __restrict__ wr = W + (size_t)(krow0 + k) * KOUT;
    #pragma unroll
    for (int j = 0; j < 4; ++j)
      #pragma unroll
      for (int o = 0; o < KOUT; ++o)
        acc[o] = fmaf(xs[j], wr[j * KOUT + o], acc[o]);
  }
}

template<int LX, bool RES>
__global__ __launch_bounds__(256)
void node_kernel(const float* x_in, const float* __restrict__ agg,
                 const float* __restrict__ W, const float* __restrict__ b,
                 float* x_out, int N)
{
  const int n = blockIdx.x * blockDim.x + threadIdx.x;
  if (n >= N) return;
  const float* x = x_in + (size_t)n * LX;
  float acc[OD_];
  #pragma unroll
  for (int o = 0; o < OD_; ++o) acc[o] = b[o];
  accum_seg<LX,   OD_>(W, 0,  x, acc);
  accum_seg<HID_, OD_>(W, LX, agg + (size_t)n * HID_, acc);
  #pragma unroll
  for (int o = 0; o < OD_; ++o) acc[o] = acc[o] >= 0.f ? acc[o] : 0.1f * acc[o];
  if constexpr (RES)
    #pragma unroll
    for (int o = 0; o < OD_; ++o) acc[o] += x[4 + o];
  const float4 x0 = *reinterpret_cast<const float4*>(x);
  float* orow = x_out + (size_t)n * OC_;
  *reinterpret_cast<float4*>(orow) = x0;
  #pragma unroll
  for (int o = 0; o < OD_; o += 4)
    *reinterpret_cast<float4*>(orow + 4 + o) =
        make_float4(acc[o], acc[o + 1], acc[o + 2], acc[o + 3]);
}

extern "C" void kernel_launch(void* const* d_in, const int* in_sizes, int n_in,
                              void* d_out, int out_size, void* d_ws, size_t ws_size,
                              hipStream_t stream)
{
  const float* x_ue    = (const float*)d_in[0];
  const float* x_ap    = (const float*)d_in[1];
  const float* ea_up   = (const float*)d_in[2];
  const float* ea_down = (const float*)d_in[3];
  const int* up_src = (const int*)d_in[4];
  const int* up_dst = (const int*)d_in[5];
  const int* dn_src = (const int*)d_in[6];
  const int* dn_dst = (const int*)d_in[7];
  const float* c1_msg_W = (const float*)d_in[8];  const float* c1_msg_b = (const float*)d_in[9];
  const float* c1_upd_W = (const float*)d_in[10]; const float* c1_upd_b = (const float*)d_in[11];
  const float* c1_ew_W  = (const float*)d_in[12]; const float* c1_ew_b  = (const float*)d_in[13];
  const float* c2_msg_W = (const float*)d_in[14]; const float* c2_msg_b = (const float*)d_in[15];
  const float* c2_upd_W = (const float*)d_in[16]; const float* c2_upd_b = (const float*)d_in[17];
  const float* c2_ew_W  = (const float*)d_in[18]; const float* c2_ew_b  = (const float*)d_in[19];
  const float* c3u_msg_W= (const float*)d_in[20]; const float* c3u_msg_b= (const float*)d_in[21];
  const float* c3u_upd_W= (const float*)d_in[22]; const float* c3u_upd_b= (const float*)d_in[23];
  const float* c3u_ew_W = (const float*)d_in[24]; const float* c3u_ew_b = (const float*)d_in[25];
  const float* c3d_msg_W= (const float*)d_in[26]; const float* c3d_msg_b= (const float*)d_in[27];
  const float* c3d_upd_W= (const float*)d_in[28]; const float* c3d_upd_b= (const float*)d_in[29];
  const float* c3d_ew_W = (const float*)d_in[30]; const float* c3d_ew_b = (const float*)d_in[31];
  const float* pe1_W = (const float*)d_in[32]; const float* pe1_b = (const float*)d_in[33];
  const float* pe2_W = (const float*)d_in[34]; const float* pe2_b = (const float*)d_in[35];
  const float* ln_g  = (const float*)d_in[36]; const float* ln_b  = (const float*)d_in[37];

  float* out    = (float*)d_out;
  float* x_ue_o = out;
  float* x_ap_o = out + (size_t)NUE_ * OC_;
  float* ea_up_o = x_ap_o + (size_t)NAP_ * OC_;
  float* ea_dn_o = ea_up_o + (size_t)EN * OC_;

  float* ws = (float*)d_ws;
  float* agg1 = ws;                          // [NAP][32]
  float* agg2 = agg1 + (size_t)NAP_ * HID_;  // [NUE][32]
  float* agg3 = agg2 + (size_t)NUE_ * HID_;  // [NAP][32]
  float* agg4 = agg3 + (size_t)NAP_ * HID_;  // [NUE][32]
  float* ea_dn_mid = agg4 + (size_t)NUE_ * HID_;          // [E][64]
  unsigned short* wb = (unsigned short*)(ea_dn_mid + (size_t)EN * OC_);
  unsigned short* we1  = wb;            // [64][32]
  unsigned short* wm1  = we1 + 2048;    // [32][32]
  unsigned short* we2  = wm1 + 1024;    // [64][96]
  unsigned short* wm2  = we2 + 6144;    // [32][96]
  unsigned short* we3u = wm2 + 3072;    // [64][192]
  unsigned short* wm3u = we3u + 12288;  // [32][128]
  unsigned short* we3d = wm3u + 4096;   // [64][192]
  unsigned short* wm3d = we3d + 12288;  // [32][128]

  hipMemsetAsync(ws, 0, sizeof(float) * (size_t)(NAP_ + NUE_) * 2 * HID_, stream);

  // weight prep (bf16, transposed, padded)
  prep_w<64, 60, 32, 12>  <<<8,  256, 0, stream>>>(c1_ew_W,  we1);
  prep_w<32, 32, 32, 8>   <<<4,  256, 0, stream>>>(c1_msg_W, wm1);
  prep_w<64, 60, 96, 72>  <<<24, 256, 0, stream>>>(c2_ew_W,  we2);
  prep_w<32, 32, 96, 68>  <<<12, 256, 0, stream>>>(c2_msg_W, wm2);
  prep_w<64, 60, 192, 192><<<48, 256, 0, stream>>>(c3u_ew_W,  we3u);
  prep_w<32, 32, 128, 128><<<16, 256, 0, stream>>>(c3u_msg_W, wm3u);
  prep_w<64, 60, 192, 192><<<48, 256, 0, stream>>>(c3d_ew_W,  we3d);
  prep_w<32, 32, 128, 128><<<16, 256, 0, stream>>>(c3d_msg_W, wm3d);

  const dim3 blk(256);
  const dim3 eg(EN / 64);

  // conv1: UE --up--> AP
  edge_mfma<4, 4, 4, 32, 32, false><<<eg, blk, 0, stream>>>(
      x_ue, ea_up, x_ap, up_src, up_dst, we1, wm1, c1_msg_b, c1_ew_b,
      agg1, ea_up_o, nullptr, nullptr, nullptr, nullptr, nullptr, nullptr);
  node_kernel<4, false><<<dim3(NAP_ / 256), blk, 0, stream>>>(
      x_ap, agg1, c1_upd_W, c1_upd_b, x_ap_o, NAP_);

  // conv2: AP --down--> UE
  edge_mfma<64, 4, 4, 96, 96, false><<<eg, blk, 0, stream>>>(
      x_ap_o, ea_down, x_ue, dn_src, dn_dst, we2, wm2, c2_msg_b, c2_ew_b,
      agg2, ea_dn_mid, nullptr, nullptr, nullptr, nullptr, nullptr, nullptr);
  node_kernel<4, false><<<dim3(NUE_ / 256), blk, 0, stream>>>(
      x_ue, agg2, c2_upd_W, c2_upd_b, x_ue_o, NUE_);

  // conv3u: UE --up--> AP (residual node), ea_up in place
  edge_mfma<64, 64, 64, 192, 128, false><<<eg, blk, 0, stream>>>(
      x_ue_o, ea_up_o, x_ap_o, up_src, up_dst, we3u, wm3u, c3u_msg_b, c3u_ew_b,
      agg3, ea_up_o, nullptr, nullptr, nullptr, nullptr, nullptr, nullptr);
  node_kernel<64, true><<<dim3(NAP_ / 256), blk, 0, stream>>>(
      x_ap_o, agg3, c3u_upd_W, c3u_upd_b, x_ap_o, NAP_);

  // conv3d: AP --down--> UE (residual node) + fused power head -> [E,5]
  edge_mfma<64, 64, 64, 192, 128, true><<<eg, blk, 0, stream>>>(
      x_ap_o, ea_dn_mid, x_ue_o, dn_src, dn_dst, we3d, wm3d, c3d_msg_b, c3d_ew_b,
      agg4, ea_dn_o, pe1_W, pe1_b, pe2_W, pe2_b, ln_g, ln_b);
  node_kernel<64, true><<<dim3(NUE_ / 256), blk, 0, stream>>>(
      x_ue_o, agg4, c3d_upd_W, c3d_upd_b, x_ue_o, NUE_);
}

// Round 4
// 943.366 us; speedup vs baseline: 4.2433x; 1.0768x over previous
//
#include <hip/hip_runtime.h>

typedef __attribute__((ext_vector_type(8))) short bf16x8;
typedef __attribute__((ext_vector_type(4))) float f32x4;

static constexpr int EN   = 524288;
static constexpr int NUE_ = 512;
static constexpr int NAP_ = 1024;
static constexpr int HID_ = 32;
static constexpr int OD_  = 60;   // OC - D
static constexpr int OC_  = 64;

__device__ __forceinline__ unsigned short f2bf(float x) {
  unsigned int u = __float_as_uint(x);
  return (unsigned short)((u + 0x7fffu + ((u >> 16) & 1u)) >> 16);  // RNE
}

// W [KREAL][NREAL] fp32 -> out [NPAD][KP] bf16 transposed, zero-padded
template<int NPAD, int NREAL, int KP, int KREAL>
__global__ __launch_bounds__(256)
void prep_w(const float* __restrict__ W, unsigned short* __restrict__ out) {
  int i = blockIdx.x * 256 + threadIdx.x;
  if (i >= NPAD * KP) return;
  int n = i / KP, k = i - n * KP;
  float v = (n < NREAL && k < KREAL) ? W[(size_t)k * NREAL + n] : 0.f;
  out[i] = f2bf(v);
}

// Fused edge stage as gather-GEMM. Block = 256 thr = 4 waves, tile = 64 edges.
// ew B-fragments read straight from global (L2-resident, prefetch depth 1);
// msg weights in LDS. Non-FUSE: direct fragment-layout stores (no Cst).
// FUSE: Cst (stride 69) + parallel power head, writes [E,5].
template<int LXJ, int LEA, int LXI, int KP, int KMP, bool FUSE>
__global__ __launch_bounds__(256, FUSE ? 3 : 4)
void edge_mfma(const float* __restrict__ x_src, const float* ea_in,
               const float* __restrict__ x_dst,
               const int* __restrict__ src_idx, const int* __restrict__ dst_idx,
               const unsigned short* __restrict__ Wet, const unsigned short* __restrict__ Wmt,
               const float* __restrict__ msg_b, const float* __restrict__ ew_b,
               float* __restrict__ agg, float* ea_out,
               const float* __restrict__ pe1_W, const float* __restrict__ pe1_b,
               const float* __restrict__ pe2_W, const float* __restrict__ pe2_b,
               const float* __restrict__ ln_g,  const float* __restrict__ ln_b)
{
  constexpr int K = LXJ + LEA + LXI;
  constexpr int KPP = KP + 8;    // Xb pad
  constexpr int KMPP = KMP + 8;
  __shared__ unsigned short Xb[64 * KPP];
  __shared__ unsigned short Wmls[32 * KMPP];
  __shared__ float Cst[FUSE ? 64 * 69 : 1];   // stride 69: 2-way max on row reads
  __shared__ float Vst[FUSE ? 64 * 4 : 1];
  const int t = threadIdx.x;
  const int eBase = blockIdx.x * 64;

  // msg weights -> LDS (uint4 = 8 ushorts)
  for (int i = t; i < 32 * (KMP / 8); i += 256) {
    int n = i / (KMP / 8), c = i - n * (KMP / 8);
    *reinterpret_cast<uint4*>(&Wmls[n * KMPP + c * 8]) =
        reinterpret_cast<const uint4*>(Wmt)[i];
  }
  // gather X rows -> bf16 LDS
  for (int i = t; i < 64 * (KP / 4); i += 256) {
    int r = i / (KP / 4), k0 = (i - r * (KP / 4)) * 4;
    int e = eBase + r;
    float4 v;
    if (k0 < LXJ)
      v = *reinterpret_cast<const float4*>(x_src + (size_t)src_idx[e] * LXJ + k0);
    else if (k0 < LXJ + LEA)
      v = *reinterpret_cast<const float4*>(ea_in + (size_t)e * LEA + (k0 - LXJ));
    else if (k0 < K)
      v = *reinterpret_cast<const float4*>(x_dst + (size_t)dst_idx[e] * LXI + (k0 - LXJ - LEA));
    else
      v = make_float4(0.f, 0.f, 0.f, 0.f);
    ushort4 o; o.x = f2bf(v.x); o.y = f2bf(v.y); o.z = f2bf(v.z); o.w = f2bf(v.w);
    *reinterpret_cast<ushort4*>(&Xb[r * KPP + k0]) = o;
  }
  __syncthreads();

  // MFMA: wave w owns edges [w*16, w*16+16)
  const int l = t & 63, w = t >> 6;
  const int lr = l & 15, lkb = l >> 4;        // A: row=lr, k-block=lkb; B: col=lr
  f32x4 accE[4] = {f32x4{0,0,0,0}, f32x4{0,0,0,0}, f32x4{0,0,0,0}, f32x4{0,0,0,0}};
  f32x4 accM[2] = {f32x4{0,0,0,0}, f32x4{0,0,0,0}};
  const unsigned short* xrow = &Xb[(w * 16 + lr) * KPP + lkb * 8];
  const unsigned short* wrow = Wet + lr * KP + lkb * 8;   // + nt*16*KP + kk*32

  bf16x8 bc[4], bn[4];
  #pragma unroll
  for (int nt = 0; nt < 4; ++nt)
    bc[nt] = *reinterpret_cast<const bf16x8*>(wrow + nt * 16 * KP);
  #pragma unroll
  for (int kk = 0; kk < KP / 32; ++kk) {
    if (kk + 1 < KP / 32) {
      #pragma unroll
      for (int nt = 0; nt < 4; ++nt)
        bn[nt] = *reinterpret_cast<const bf16x8*>(wrow + nt * 16 * KP + (kk + 1) * 32);
    }
    bf16x8 a = *reinterpret_cast<const bf16x8*>(xrow + kk * 32);
    #pragma unroll
    for (int nt = 0; nt < 4; ++nt)
      accE[nt] = __builtin_amdgcn_mfma_f32_16x16x32_bf16(a, bc[nt], accE[nt], 0, 0, 0);
    if (kk < KMP / 32) {
      #pragma unroll
      for (int nt = 0; nt < 2; ++nt) {
        bf16x8 b = *reinterpret_cast<const bf16x8*>(&Wmls[(nt * 16 + lr) * KMPP + lkb * 8 + kk * 32]);
        accM[nt] = __builtin_amdgcn_mfma_f32_16x16x32_bf16(a, b, accM[nt], 0, 0, 0);
      }
    }
    #pragma unroll
    for (int nt = 0; nt < 4; ++nt) bc[nt] = bn[nt];
  }

  // msg: bias + lrelu + scatter-add.  C/D layout: col=lane&15, row=(lane>>4)*4+reg
  #pragma unroll
  for (int r = 0; r < 4; ++r) {
    int erow = w * 16 + lkb * 4 + r;
    int dst = dst_idx[eBase + erow];
    #pragma unroll
    for (int nt = 0; nt < 2; ++nt) {
      int col = nt * 16 + lr;
      float v = accM[nt][r] + msg_b[col];
      v = v >= 0.f ? v : 0.1f * v;
      atomicAdd(&agg[(size_t)dst * HID_ + col], v);
    }
  }

  if constexpr (!FUSE) {
    // ew: bias + lrelu, direct fragment-layout stores (cols 4..63)
    #pragma unroll
    for (int r = 0; r < 4; ++r) {
      const int erow = w * 16 + lkb * 4 + r;
      float* orow = ea_out + (size_t)(eBase + erow) * OC_;
      #pragma unroll
      for (int nt = 0; nt < 4; ++nt) {
        int c = nt * 16 + lr;
        if (c < OD_) {
          float v = accE[nt][r] + ew_b[c];
          orow[4 + c] = v >= 0.f ? v : 0.1f * v;
        }
      }
    }
    // passthrough cols 0..3
    if (t < 64) {
      size_t e = eBase + t;
      float4 v = *reinterpret_cast<const float4*>(ea_in + e * LEA);
      *reinterpret_cast<float4*>(ea_out + e * OC_) = v;
    }
  } else {
    // stage ew rows for the power head
    #pragma unroll
    for (int nt = 0; nt < 4; ++nt) {
      int col = nt * 16 + lr;
      float bias = col < OD_ ? ew_b[col] : 0.f;
      #pragma unroll
      for (int r = 0; r < 4; ++r) {
        int erow = w * 16 + lkb * 4 + r;
        float v = accE[nt][r] + bias;
        Cst[erow * 69 + col] = v >= 0.f ? v : 0.1f * v;
      }
    }
    __syncthreads();
    // power head Lin(64->4): thread (r = t&63, j = t>>6)
    {
      const int r = t & 63, j = t >> 6;
      size_t e = eBase + r;
      const float* ear = ea_in + e * LEA;
      float acc = pe1_b[j];
      #pragma unroll
      for (int k = 0; k < 4; ++k) acc = fmaf(ear[k], pe1_W[k * 4 + j], acc);
      #pragma unroll 4
      for (int k = 0; k < OD_; ++k) acc = fmaf(Cst[r * 69 + k], pe1_W[(4 + k) * 4 + j], acc);
      Vst[r * 4 + j] = acc;
    }
    __syncthreads();
    if (t < 64) {
      size_t e = eBase + t;
      const float* ear = ea_in + e * LEA;
      float v4[4] = {Vst[t * 4], Vst[t * 4 + 1], Vst[t * 4 + 2], Vst[t * 4 + 3]};
      float mu = 0.25f * (v4[0] + v4[1] + v4[2] + v4[3]);
      float var = 0.f;
      #pragma unroll
      for (int j = 0; j < 4; ++j) { float d = v4[j] - mu; var = fmaf(d, d, var); }
      var *= 0.25f;
      float rstd = rsqrtf(var + 1e-5f);
      float p = pe2_b[0];
      #pragma unroll
      for (int j = 0; j < 4; ++j) {
        float h = (v4[j] - mu) * rstd * ln_g[j] + ln_b[j];
        h = h >= 0.f ? h : 0.1f * h;
        p = fmaf(h, pe2_W[j], p);
      }
      float* orow = ea_out + e * 5;
      orow[0] = ear[0]; orow[1] = ear[1]; orow[2] = ear[2]; orow[3] = ear[3]; orow[4] = p;
    }
  }
}

// ---- scalar fp32 node update (tiny: 512/1024 rows) ----
template<int L, int KOUT>
__device__ __forceinline__ void accum_seg(const float* __restrict__ W, int krow0,
                                          const float* seg, float* acc) {
  #pragma unroll 1
  for (int k = 0; k < L; k += 4) {
    const float4 x = *reinterpret_cast<const float4*>(seg + k);
    const float xs[4] = {x.x, x.y, x.z, x.w};
    const float* __restrict__ wr = W + (size_t)(krow0 + k) * KOUT;
    #pragma unroll
    for (int j = 0; j < 4; ++j)
      #pragma unroll
      for (int o = 0; o < KOUT; ++o)
        acc[o] = fmaf(xs[j], wr[j * KOUT + o], acc[o]);
  }
}

template<int LX, bool RES>
__global__ __launch_bounds__(256)
void node_kernel(const float* x_in, const float* __restrict__ agg,
                 const float* __restrict__ W, const float* __restrict__ b,
                 float* x_out, int N)
{
  const int n = blockIdx.x * blockDim.x + threadIdx.x;
  if (n >= N) return;
  const float* x = x_in + (size_t)n * LX;
  float acc[OD_];
  #pragma unroll
  for (int o = 0; o < OD_; ++o) acc[o] = b[o];
  accum_seg<LX,   OD_>(W, 0,  x, acc);
  accum_seg<HID_, OD_>(W, LX, agg + (size_t)n * HID_, acc);
  #pragma unroll
  for (int o = 0; o < OD_; ++o) acc[o] = acc[o] >= 0.f ? acc[o] : 0.1f * acc[o];
  if constexpr (RES)
    #pragma unroll
    for (int o = 0; o < OD_; ++o) acc[o] += x[4 + o];
  const float4 x0 = *reinterpret_cast<const float4*>(x);
  float* orow = x_out + (size_t)n * OC_;
  *reinterpret_cast<float4*>(orow) = x0;
  #pragma unroll
  for (int o = 0; o < OD_; o += 4)
    *reinterpret_cast<float4*>(orow + 4 + o) =
        make_float4(acc[o], acc[o + 1], acc[o + 2], acc[o + 3]);
}

extern "C" void kernel_launch(void* const* d_in, const int* in_sizes, int n_in,
                              void* d_out, int out_size, void* d_ws, size_t ws_size,
                              hipStream_t stream)
{
  const float* x_ue    = (const float*)d_in[0];
  const float* x_ap    = (const float*)d_in[1];
  const float* ea_up   = (const float*)d_in[2];
  const float* ea_down = (const float*)d_in[3];
  const int* up_src = (const int*)d_in[4];
  const int* up_dst = (const int*)d_in[5];
  const int* dn_src = (const int*)d_in[6];
  const int* dn_dst = (const int*)d_in[7];
  const float* c1_msg_W = (const float*)d_in[8];  const float* c1_msg_b = (const float*)d_in[9];
  const float* c1_upd_W = (const float*)d_in[10]; const float* c1_upd_b = (const float*)d_in[11];
  const float* c1_ew_W  = (const float*)d_in[12]; const float* c1_ew_b  = (const float*)d_in[13];
  const float* c2_msg_W = (const float*)d_in[14]; const float* c2_msg_b = (const float*)d_in[15];
  const float* c2_upd_W = (const float*)d_in[16]; const float* c2_upd_b = (const float*)d_in[17];
  const float* c2_ew_W  = (const float*)d_in[18]; const float* c2_ew_b  = (const float*)d_in[19];
  const float* c3u_msg_W= (const float*)d_in[20]; const float* c3u_msg_b= (const float*)d_in[21];
  const float* c3u_upd_W= (const float*)d_in[22]; const float* c3u_upd_b= (const float*)d_in[23];
  const float* c3u_ew_W = (const float*)d_in[24]; const float* c3u_ew_b = (const float*)d_in[25];
  const float* c3d_msg_W= (const float*)d_in[26]; const float* c3d_msg_b= (const float*)d_in[27];
  const float* c3d_upd_W= (const float*)d_in[28]; const float* c3d_upd_b= (const float*)d_in[29];
  const float* c3d_ew_W = (const float*)d_in[30]; const float* c3d_ew_b = (const float*)d_in[31];
  const float* pe1_W = (const float*)d_in[32]; const float* pe1_b = (const float*)d_in[33];
  const float* pe2_W = (const float*)d_in[34]; const float* pe2_b = (const float*)d_in[35];
  const float* ln_g  = (const float*)d_in[36]; const float* ln_b  = (const float*)d_in[37];

  float* out    = (float*)d_out;
  float* x_ue_o = out;
  float* x_ap_o = out + (size_t)NUE_ * OC_;
  float* ea_up_o = x_ap_o + (size_t)NAP_ * OC_;
  float* ea_dn_o = ea_up_o + (size_t)EN * OC_;

  float* ws = (float*)d_ws;
  float* agg1 = ws;                          // [NAP][32]
  float* agg2 = agg1 + (size_t)NAP_ * HID_;  // [NUE][32]
  float* agg3 = agg2 + (size_t)NUE_ * HID_;  // [NAP][32]
  float* agg4 = agg3 + (size_t)NAP_ * HID_;  // [NUE][32]
  float* ea_dn_mid = agg4 + (size_t)NUE_ * HID_;          // [E][64]
  unsigned short* wb = (unsigned short*)(ea_dn_mid + (size_t)EN * OC_);
  unsigned short* we1  = wb;            // [64][32]
  unsigned short* wm1  = we1 + 2048;    // [32][32]
  unsigned short* we2  = wm1 + 1024;    // [64][96]
  unsigned short* wm2  = we2 + 6144;    // [32][96]
  unsigned short* we3u = wm2 + 3072;    // [64][192]
  unsigned short* wm3u = we3u + 12288;  // [32][128]
  unsigned short* we3d = wm3u + 4096;   // [64][192]
  unsigned short* wm3d = we3d + 12288;  // [32][128]

  hipMemsetAsync(ws, 0, sizeof(float) * (size_t)(NAP_ + NUE_) * 2 * HID_, stream);

  // weight prep (bf16, transposed, padded)
  prep_w<64, 60, 32, 12>  <<<8,  256, 0, stream>>>(c1_ew_W,  we1);
  prep_w<32, 32, 32, 8>   <<<4,  256, 0, stream>>>(c1_msg_W, wm1);
  prep_w<64, 60, 96, 72>  <<<24, 256, 0, stream>>>(c2_ew_W,  we2);
  prep_w<32, 32, 96, 68>  <<<12, 256, 0, stream>>>(c2_msg_W, wm2);
  prep_w<64, 60, 192, 192><<<48, 256, 0, stream>>>(c3u_ew_W,  we3u);
  prep_w<32, 32, 128, 128><<<16, 256, 0, stream>>>(c3u_msg_W, wm3u);
  prep_w<64, 60, 192, 192><<<48, 256, 0, stream>>>(c3d_ew_W,  we3d);
  prep_w<32, 32, 128, 128><<<16, 256, 0, stream>>>(c3d_msg_W, wm3d);

  const dim3 blk(256);
  const dim3 eg(EN / 64);

  // conv1: UE --up--> AP
  edge_mfma<4, 4, 4, 32, 32, false><<<eg, blk, 0, stream>>>(
      x_ue, ea_up, x_ap, up_src, up_dst, we1, wm1, c1_msg_b, c1_ew_b,
      agg1, ea_up_o, nullptr, nullptr, nullptr, nullptr, nullptr, nullptr);
  node_kernel<4, false><<<dim3(NAP_ / 256), blk, 0, stream>>>(
      x_ap, agg1, c1_upd_W, c1_upd_b, x_ap_o, NAP_);

  // conv2: AP --down--> UE
  edge_mfma<64, 4, 4, 96, 96, false><<<eg, blk, 0, stream>>>(
      x_ap_o, ea_down, x_ue, dn_src, dn_dst, we2, wm2, c2_msg_b, c2_ew_b,
      agg2, ea_dn_mid, nullptr, nullptr, nullptr, nullptr, nullptr, nullptr);
  node_kernel<4, false><<<dim3(NUE_ / 256), blk, 0, stream>>>(
      x_ue, agg2, c2_upd_W, c2_upd_b, x_ue_o, NUE_);

  // conv3u: UE --up--> AP (residual node), ea_up in place
  edge_mfma<64, 64, 64, 192, 128, false><<<eg, blk, 0, stream>>>(
      x_ue_o, ea_up_o, x_ap_o, up_src, up_dst, we3u, wm3u, c3u_msg_b, c3u_ew_b,
      agg3, ea_up_o, nullptr, nullptr, nullptr, nullptr, nullptr, nullptr);
  node_kernel<64, true><<<dim3(NAP_ / 256), blk, 0, stream>>>(
      x_ap_o, agg3, c3u_upd_W, c3u_upd_b, x_ap_o, NAP_);

  // conv3d: AP --down--> UE (residual node) + fused power head -> [E,5]
  edge_mfma<64, 64, 64, 192, 128, true><<<eg, blk, 0, stream>>>(
      x_ap_o, ea_dn_mid, x_ue_o, dn_src, dn_dst, we3d, wm3d, c3d_msg_b, c3d_ew_b,
      agg4, ea_dn_o, pe1_W, pe1_b, pe2_W, pe2_b, ln_g, ln_b);
  node_kernel<64, true><<<dim3(NUE_ / 256), blk, 0, stream>>>(
      x_ue_o, agg4, c3d_upd_W, c3d_upd_b, x_ue_o, NUE_);
}